// Round 3
// baseline (196.240 us; speedup 1.0000x reference)
//
#include <hip/hip_runtime.h>

// DiscriminativeLoss: reference output == prediction.sum() exactly.
// Every pixel's label lies in [0, N_INSTANCE_BINS), so the one-hot masks
// sum to 1 at every location and the einsum collapses to a full sum of
// `prediction`. `target` is mathematically dead — never read it.
// Memory-bound: 134 MB read -> ~21 us floor at 6.3 TB/s achievable.

#define BLOCK 256
#define GRID1 2048   // 256 CUs * 8 blocks/CU

__global__ __launch_bounds__(BLOCK) void sum_stage1(
    const float* __restrict__ in, long long n, float* __restrict__ partial) {
  const long long n4 = n >> 2;  // float4 chunks
  const float4* __restrict__ in4 = (const float4*)in;

  const long long tid    = (long long)blockIdx.x * BLOCK + threadIdx.x;
  const long long stride = (long long)gridDim.x * BLOCK;

  // Two independent accumulators + unroll-by-2: two dwordx4 loads in
  // flight per iteration, no serial FP-add dependence between them.
  float acc0 = 0.0f, acc1 = 0.0f;
  long long i = tid;
  for (; i + stride < n4; i += 2 * stride) {
    float4 a = in4[i];
    float4 b = in4[i + stride];
    acc0 += (a.x + a.y) + (a.z + a.w);
    acc1 += (b.x + b.y) + (b.z + b.w);
  }
  if (i < n4) {
    float4 a = in4[i];
    acc0 += (a.x + a.y) + (a.z + a.w);
  }
  float acc = acc0 + acc1;
  // scalar tail (n % 4 != 0) — empty for this shape, kept for safety
  for (long long j = (n4 << 2) + tid; j < n; j += stride) acc += in[j];

  // wave-64 butterfly reduce
  #pragma unroll
  for (int off = 32; off > 0; off >>= 1) acc += __shfl_down(acc, off, 64);

  __shared__ float smem[BLOCK / 64];
  const int lane = threadIdx.x & 63;
  const int wid  = threadIdx.x >> 6;
  if (lane == 0) smem[wid] = acc;
  __syncthreads();
  if (threadIdx.x == 0) {
    float s = 0.0f;
    #pragma unroll
    for (int k = 0; k < BLOCK / 64; ++k) s += smem[k];
    partial[blockIdx.x] = s;
  }
}

__global__ __launch_bounds__(BLOCK) void sum_stage2(
    const float* __restrict__ partial, int n, float* __restrict__ out) {
  float acc = 0.0f;
  for (int i = threadIdx.x; i < n; i += BLOCK) acc += partial[i];
  #pragma unroll
  for (int off = 32; off > 0; off >>= 1) acc += __shfl_down(acc, off, 64);

  __shared__ float smem[BLOCK / 64];
  const int lane = threadIdx.x & 63;
  const int wid  = threadIdx.x >> 6;
  if (lane == 0) smem[wid] = acc;
  __syncthreads();
  if (threadIdx.x == 0) {
    float s = 0.0f;
    #pragma unroll
    for (int k = 0; k < BLOCK / 64; ++k) s += smem[k];
    out[0] = s;
  }
}

extern "C" void kernel_launch(void* const* d_in, const int* in_sizes, int n_in,
                              void* d_out, int out_size, void* d_ws, size_t ws_size,
                              hipStream_t stream) {
  const float* pred = (const float*)d_in[0];
  // d_in[1] (target, int32) is mathematically dead: one-hot masks sum to 1.
  const long long n = (long long)in_sizes[0];
  float* out = (float*)d_out;
  float* partial = (float*)d_ws;  // GRID1 floats, well within ws_size

  sum_stage1<<<GRID1, BLOCK, 0, stream>>>(pred, n, partial);
  sum_stage2<<<1, BLOCK, 0, stream>>>(partial, GRID1, out);
}

// Round 4
// 189.111 us; speedup vs baseline: 1.0377x; 1.0377x over previous
//
#include <hip/hip_runtime.h>

// DiscriminativeLoss: reference output == prediction.sum() exactly.
// Every pixel's label lies in [0, N_INSTANCE_BINS), so the one-hot masks
// sum to 1 at every location and the einsum collapses to a full sum of
// `prediction`. `target` is mathematically dead — never read it.
// Memory-bound: 134 MB read -> ~21 us floor at 6.3 TB/s achievable.
//
// R3 evidence: total dur_us=196 is dominated by harness reset dispatches
// (512MB ws re-poison @ 77us + ~57us input restore); our kernels are the
// remaining ~30-50us. This round: nt loads (134MB stream > 32MB L2, read
// once — don't allocate in cache) + compile-time stride. Accumulation
// order unchanged -> result stays bit-identical (absmax was 0.0).

#define BLOCK 256
#define GRID1 2048   // 256 CUs * 8 blocks/CU = full occupancy (8192 waves)

typedef float floatx4 __attribute__((ext_vector_type(4)));

__global__ __launch_bounds__(BLOCK) void sum_stage1(
    const float* __restrict__ in, long long n, float* __restrict__ partial) {
  const long long n4 = n >> 2;  // float4 chunks
  const floatx4* __restrict__ in4 = (const floatx4*)in;

  const long long tid    = (long long)blockIdx.x * BLOCK + threadIdx.x;
  const long long stride = (long long)GRID1 * BLOCK;  // compile-time constant

  // Two independent accumulators + unroll-by-2: two nt dwordx4 loads in
  // flight per iteration, no serial FP-add dependence between them.
  // Same lane->element mapping and FP order as R3 (bit-exact result).
  float acc0 = 0.0f, acc1 = 0.0f;
  long long i = tid;
  for (; i + stride < n4; i += 2 * stride) {
    floatx4 a = __builtin_nontemporal_load(&in4[i]);
    floatx4 b = __builtin_nontemporal_load(&in4[i + stride]);
    acc0 += (a.x + a.y) + (a.z + a.w);
    acc1 += (b.x + b.y) + (b.z + b.w);
  }
  if (i < n4) {
    floatx4 a = __builtin_nontemporal_load(&in4[i]);
    acc0 += (a.x + a.y) + (a.z + a.w);
  }
  float acc = acc0 + acc1;
  // scalar tail (n % 4 != 0) — empty for this shape, kept for safety
  for (long long j = (n4 << 2) + tid; j < n; j += stride) acc += in[j];

  // wave-64 butterfly reduce
  #pragma unroll
  for (int off = 32; off > 0; off >>= 1) acc += __shfl_down(acc, off, 64);

  __shared__ float smem[BLOCK / 64];
  const int lane = threadIdx.x & 63;
  const int wid  = threadIdx.x >> 6;
  if (lane == 0) smem[wid] = acc;
  __syncthreads();
  if (threadIdx.x == 0) {
    float s = 0.0f;
    #pragma unroll
    for (int k = 0; k < BLOCK / 64; ++k) s += smem[k];
    partial[blockIdx.x] = s;
  }
}

__global__ __launch_bounds__(BLOCK) void sum_stage2(
    const float* __restrict__ partial, int n, float* __restrict__ out) {
  float acc = 0.0f;
  for (int i = threadIdx.x; i < n; i += BLOCK) acc += partial[i];
  #pragma unroll
  for (int off = 32; off > 0; off >>= 1) acc += __shfl_down(acc, off, 64);

  __shared__ float smem[BLOCK / 64];
  const int lane = threadIdx.x & 63;
  const int wid  = threadIdx.x >> 6;
  if (lane == 0) smem[wid] = acc;
  __syncthreads();
  if (threadIdx.x == 0) {
    float s = 0.0f;
    #pragma unroll
    for (int k = 0; k < BLOCK / 64; ++k) s += smem[k];
    out[0] = s;
  }
}

extern "C" void kernel_launch(void* const* d_in, const int* in_sizes, int n_in,
                              void* d_out, int out_size, void* d_ws, size_t ws_size,
                              hipStream_t stream) {
  const float* pred = (const float*)d_in[0];
  // d_in[1] (target, int32) is mathematically dead: one-hot masks sum to 1.
  const long long n = (long long)in_sizes[0];
  float* out = (float*)d_out;
  float* partial = (float*)d_ws;  // GRID1 floats, well within ws_size

  sum_stage1<<<GRID1, BLOCK, 0, stream>>>(pred, n, partial);
  sum_stage2<<<1, BLOCK, 0, stream>>>(partial, GRID1, out);
}